// Round 1
// baseline (826.235 us; speedup 1.0000x reference)
//
#include <hip/hip_runtime.h>
#include <stdint.h>

typedef float f32x4 __attribute__((ext_vector_type(4)));
typedef short s16x8 __attribute__((ext_vector_type(8)));
typedef short s16x4 __attribute__((ext_vector_type(4)));

#define MFMA16(a, b, c) __builtin_amdgcn_mfma_f32_16x16x32_bf16(a, b, c, 0, 0, 0)

__device__ __forceinline__ unsigned short f2bf(float f) {
  union { float f; uint32_t u; } v; v.f = f;
  return (unsigned short)((v.u + 0x7FFFu + ((v.u >> 16) & 1u)) >> 16);
}
__device__ __forceinline__ float bf2f(unsigned short s) {
  union { float f; uint32_t u; } v; v.u = ((uint32_t)s) << 16;
  return v.f;
}
// load 8 consecutive fp32, convert to bf16x8 fragment
__device__ __forceinline__ s16x8 cvt8(const float* p) {
  f32x4 a = *(const f32x4*)p;
  f32x4 b = *(const f32x4*)(p + 4);
  s16x8 t;
  t[0] = (short)f2bf(a[0]); t[1] = (short)f2bf(a[1]);
  t[2] = (short)f2bf(a[2]); t[3] = (short)f2bf(a[3]);
  t[4] = (short)f2bf(b[0]); t[5] = (short)f2bf(b[1]);
  t[6] = (short)f2bf(b[2]); t[7] = (short)f2bf(b[3]);
  return t;
}

// ---------------------------------------------------------------------------
// Stage 1: Y = X @ W^T + b  (262144 x 128 rows, K=128), output bf16.
// blockIdx.y selects tensor: 0=query -> Qt, 1=key -> Kt (per-head [h][c]
// transposed layout), 2=value -> Vf (flat row-major = per-head [c][h']).
// Flat index identity: for global row j, feature cc:
//   head n = j>>9,  h = (j&3)*128 + cc,  c = (j&511)>>2.
// ---------------------------------------------------------------------------
__global__ __launch_bounds__(256) void proj_kernel(
    const float* __restrict__ Xq, const float* __restrict__ Xk, const float* __restrict__ Xv,
    const float* __restrict__ Wq, const float* __restrict__ bq,
    const float* __restrict__ Wk, const float* __restrict__ bk,
    const float* __restrict__ Wv, const float* __restrict__ bv,
    unsigned short* __restrict__ Qt, unsigned short* __restrict__ Kt,
    unsigned short* __restrict__ Vf) {
  const int ty = blockIdx.y;
  const float* X = (ty == 0) ? Xq : (ty == 1) ? Xk : Xv;
  const float* W = (ty == 0) ? Wq : (ty == 1) ? Wk : Wv;
  const float* B = (ty == 0) ? bq : (ty == 1) ? bk : bv;
  unsigned short* out = (ty == 0) ? Qt : (ty == 1) ? Kt : Vf;
  const bool transposed = (ty != 2);

  const int tid = threadIdx.x;
  const int lane = tid & 63;
  const int wave = tid >> 6;
  const int l15 = lane & 15;
  const int g = lane >> 4;  // 0..3

  // W fragments resident in VGPRs: wf[f][kc] = W[16f + l15][32kc + 8g .. +7]
  s16x8 wf[8][4];
#pragma unroll
  for (int f = 0; f < 8; ++f) {
    const float* wr = W + (size_t)(16 * f + l15) * 128 + 8 * g;
#pragma unroll
    for (int kc = 0; kc < 4; ++kc) wf[f][kc] = cvt8(wr + 32 * kc);
  }

  if (transposed) {
    // bias: C col = cc = 16f + l15 (fixed per lane)
    float bias_s[8];
#pragma unroll
    for (int f = 0; f < 8; ++f) bias_s[f] = B[16 * f + l15];

    for (int t = 0; t < 8; ++t) {
      const int jb = blockIdx.x * 512 + t * 64 + wave * 16;
      // permuted row feed: MFMA row m -> global row jb + (m>>2) + 4*(m&3)
      const int jrow = jb + (l15 >> 2) + 4 * (l15 & 3);
      const float* xr = X + (size_t)jrow * 128 + 8 * g;
      s16x8 xf[4];
#pragma unroll
      for (int kc = 0; kc < 4; ++kc) xf[kc] = cvt8(xr + 32 * kc);

      f32x4 acc[8];
#pragma unroll
      for (int f = 0; f < 8; ++f) acc[f] = (f32x4){0.f, 0.f, 0.f, 0.f};
#pragma unroll
      for (int kc = 0; kc < 4; ++kc)
#pragma unroll
        for (int f = 0; f < 8; ++f) acc[f] = MFMA16(xf[kc], wf[f][kc], acc[f]);

      // C rows (reg r) -> j = jb + g + 4r -> c = c0 + r (consecutive!), h fixed
      const int n = jb >> 9;
      const int c0 = (jb & 511) >> 2;
#pragma unroll
      for (int f = 0; f < 8; ++f) {
        const int h = 128 * g + 16 * f + l15;
        s16x4 pv;
#pragma unroll
        for (int r = 0; r < 4; ++r) pv[r] = (short)f2bf(acc[f][r] + bias_s[f]);
        *(s16x4*)(out + (size_t)n * 65536 + (size_t)h * 128 + c0) = pv;
      }
    }
  } else {
    // swapped operands: D[cc][j]; bias rows cc = 16f + 4g + r
    f32x4 bias_v[8];
#pragma unroll
    for (int f = 0; f < 8; ++f) bias_v[f] = *(const f32x4*)(B + 16 * f + 4 * g);

    for (int t = 0; t < 8; ++t) {
      const int jb = blockIdx.x * 512 + t * 64 + wave * 16;
      const int jrow = jb + l15;
      const float* xr = X + (size_t)jrow * 128 + 8 * g;
      s16x8 xf[4];
#pragma unroll
      for (int kc = 0; kc < 4; ++kc) xf[kc] = cvt8(xr + 32 * kc);

      f32x4 acc[8];
#pragma unroll
      for (int f = 0; f < 8; ++f) acc[f] = (f32x4){0.f, 0.f, 0.f, 0.f};
#pragma unroll
      for (int kc = 0; kc < 4; ++kc)
#pragma unroll
        for (int f = 0; f < 8; ++f) acc[f] = MFMA16(wf[f][kc], xf[kc], acc[f]);

      const int j = jb + l15;
#pragma unroll
      for (int f = 0; f < 8; ++f) {
        const int cc0 = 16 * f + 4 * g;
        s16x4 pv;
#pragma unroll
        for (int r = 0; r < 4; ++r) pv[r] = (short)f2bf(acc[f][r] + bias_v[f][r]);
        *(s16x4*)(out + (size_t)j * 128 + cc0) = pv;
      }
    }
  }
}

// ---------------------------------------------------------------------------
// Stage 2: per (head, 64-row Q tile): S = Q K^T * scale, exp, rowsum,
// attn = expS/rowsum (fp32 out), ctxt = attn @ V (fp32 out).
// P (unnormalized exp) lives in 64KB XOR-swizzled LDS.
// ---------------------------------------------------------------------------
__global__ __launch_bounds__(256) void attn_kernel(
    const unsigned short* __restrict__ Qt, const unsigned short* __restrict__ Kt,
    const unsigned short* __restrict__ Vf, float* __restrict__ out0,
    float* __restrict__ attn_out) {
  __shared__ unsigned char Psh[65536];  // P[64][512] bf16, byte ^= (row&7)<<4

  const int tid = threadIdx.x;
  const int lane = tid & 63;
  const int wave = tid >> 6;
  const int l15 = lane & 15;
  const int g = lane >> 4;

  // XCD-aware bijective swizzle (4096 % 8 == 0): all 8 tiles of a head on one XCD
  const int bid = blockIdx.x;
  const int nb = (bid & 7) * 512 + (bid >> 3);
  const int head = nb >> 3;
  const int h0 = (nb & 7) * 64;

  // Q fragments for this wave's 16 rows
  const unsigned short* qbase =
      Qt + (size_t)head * 65536 + (size_t)(h0 + 16 * wave + l15) * 128 + 8 * g;
  s16x8 qf[4];
#pragma unroll
  for (int kc = 0; kc < 4; ++kc) qf[kc] = *(const s16x8*)(qbase + 32 * kc);

  const unsigned short* kbase = Kt + (size_t)head * 65536 + (size_t)l15 * 128 + 8 * g;
  float rsum[4] = {0.f, 0.f, 0.f, 0.f};

  auto loadK = [&](s16x8* kf, int hc) {
    const unsigned short* kp = kbase + hc * 2048;
#pragma unroll
    for (int kc = 0; kc < 4; ++kc) kf[kc] = *(const s16x8*)(kp + 32 * kc);
  };
  auto computeS = [&](const s16x8* kf, int hc) {
    f32x4 acc = {0.f, 0.f, 0.f, 0.f};
#pragma unroll
    for (int kc = 0; kc < 4; ++kc) acc = MFMA16(qf[kc], kf[kc], acc);
#pragma unroll
    for (int r = 0; r < 4; ++r) {
      float e = __expf(acc[r] * 0.08838834764831845f);  // 1/sqrt(128)
      rsum[r] += e;
      const int row = 16 * wave + 4 * g + r;
      const int byte = (row * 1024 + hc * 32 + l15 * 2) ^ ((row & 7) << 4);
      *(unsigned short*)(Psh + byte) = f2bf(e);
    }
  };

  s16x8 ka[4], kb[4];
  loadK(ka, 0);
  for (int hc = 0; hc < 32; hc += 2) {
    loadK(kb, hc + 1);
    computeS(ka, hc);
    if (hc + 2 < 32) loadK(ka, hc + 2);
    computeS(kb, hc + 1);
  }

  // rowsum: reduce over the 16 lanes (columns) of each row group
#pragma unroll
  for (int r = 0; r < 4; ++r) {
    float s = rsum[r];
    s += __shfl_xor(s, 1); s += __shfl_xor(s, 2);
    s += __shfl_xor(s, 4); s += __shfl_xor(s, 8);
    rsum[r] = s;
  }
  float inv[4];
#pragma unroll
  for (int r = 0; r < 4; ++r) inv[r] = 1.0f / rsum[r];

  __syncthreads();

  // phase 2: coalesced fp32 attn write (wave writes its own 16 rows)
  {
    float* ap = attn_out + (size_t)head * 262144 + (size_t)(h0 + 16 * wave) * 512;
#pragma unroll
    for (int i = 0; i < 32; ++i) {
      const int row16 = i >> 1;  // compile-time after unroll
      const int row = 16 * wave + row16;
      const float is = __shfl(inv[row16 & 3], (row16 >> 2) << 4);
      const int byte = (row * 1024 + (i & 1) * 512 + lane * 8) ^ ((row & 7) << 4);
      s16x4 pv = *(const s16x4*)(Psh + byte);
      f32x4 o;
      o[0] = bf2f((unsigned short)pv[0]) * is;
      o[1] = bf2f((unsigned short)pv[1]) * is;
      o[2] = bf2f((unsigned short)pv[2]) * is;
      o[3] = bf2f((unsigned short)pv[3]) * is;
      *(f32x4*)(ap + (size_t)row16 * 512 + (i & 1) * 256 + lane * 4) = o;
    }
  }

  // phase 3: ctxt = P @ V  (P A-frags from LDS, V B-frags direct from global)
  f32x4 acc2[8];
#pragma unroll
  for (int f = 0; f < 8; ++f) acc2[f] = (f32x4){0.f, 0.f, 0.f, 0.f};

  const unsigned short* vbase = Vf + (size_t)head * 65536 + (size_t)l15 * 512 + 8 * g;
  const int prow = 16 * wave + l15;
  const int psw = (prow & 7) << 4;

  auto loadV = [&](s16x8* vf, int hc) {
    const unsigned short* vp = vbase + hc * 32;
#pragma unroll
    for (int f = 0; f < 8; ++f) vf[f] = *(const s16x8*)(vp + f * 8192);
  };
  auto pvStep = [&](const s16x8* vf, int hc) {
    const int byte = prow * 1024 + ((hc * 64 + g * 16) ^ psw);
    s16x8 pa = *(const s16x8*)(Psh + byte);
#pragma unroll
    for (int f = 0; f < 8; ++f) acc2[f] = MFMA16(pa, vf[f], acc2[f]);
  };

  s16x8 va[8], vb[8];
  loadV(va, 0);
  for (int hc = 0; hc < 16; hc += 2) {
    loadV(vb, hc + 1);
    pvStep(va, hc);
    if (hc + 2 < 16) loadV(va, hc + 2);
    pvStep(vb, hc + 1);
  }

  // phase 4: ctxt store (normalized), 64B-contiguous per 16-lane group
  float* op = out0 + (size_t)head * 65536 + (size_t)(h0 + 16 * wave + 4 * g) * 128 + l15;
#pragma unroll
  for (int f = 0; f < 8; ++f)
#pragma unroll
    for (int r = 0; r < 4; ++r) op[(size_t)r * 128 + f * 16] = acc2[f][r] * inv[r];
}

extern "C" void kernel_launch(void* const* d_in, const int* in_sizes, int n_in,
                              void* d_out, int out_size, void* d_ws, size_t ws_size,
                              hipStream_t stream) {
  const float* q  = (const float*)d_in[0];
  const float* k  = (const float*)d_in[1];
  const float* v  = (const float*)d_in[2];
  const float* Wq = (const float*)d_in[3];
  const float* bq = (const float*)d_in[4];
  const float* Wk = (const float*)d_in[5];
  const float* bk = (const float*)d_in[6];
  const float* Wv = (const float*)d_in[7];
  const float* bv = (const float*)d_in[8];

  unsigned short* Qt = (unsigned short*)d_ws;       // 512*512*128 bf16 = 64 MiB
  unsigned short* Kt = Qt + 33554432;               // 64 MiB
  unsigned short* Vf = Kt + 33554432;               // 64 MiB
  float* out0 = (float*)d_out;                      // 33,554,432 fp32
  float* attn = out0 + 33554432;                    // 134,217,728 fp32

  dim3 pgrid(512, 3, 1);
  proj_kernel<<<pgrid, 256, 0, stream>>>(q, k, v, Wq, bq, Wk, bk, Wv, bv, Qt, Kt, Vf);
  attn_kernel<<<4096, 256, 0, stream>>>(Qt, Kt, Vf, out0, attn);
}